// Round 6
// baseline (270.431 us; speedup 1.0000x reference)
//
#include <hip/hip_runtime.h>
#include <math.h>

// Problem constants (B=2, H=8, S=2048, D=64)
#define BH_    16
#define S_     2048
#define D_     64
#define KELEMS (BH_ * S_ * D_)       // 2,097,152 K elements
#define NROWS  (BH_ * S_)            // 32,768 query rows

// ---- two-phase path geometry
#define CAPG   1024     // global candidate cap/row (worst-row estimate ~420)
#define SUPC   256      // support cap/row in phase B (worst-row est ~120; R5
                        // passed with 256 total candidates => support <= 256)
#define QT_A   16       // queries per phase-A block (MFMA M)
#define KSEG   512      // keys per phase-A block (4 segments over S)
#define KTW_A  8        // 16-key tiles per wave (128 keys/wave, 4 waves)
#define ITW_A  7        // wave-local Newton iterations (fixed, from below)
#define BMAXIT 24       // phase-B Newton max iterations

// ---- fallback (R5 single-kernel) geometry
#define QT_F    32
#define BLOCK_F 1024
#define NW_F    16
#define KTW_F   8
#define CAP_F   256
#define ITPRE_F 5
#define WMAXIT_F 16

typedef __attribute__((ext_vector_type(8))) short bf16x8;   // 8 bf16 = 4 VGPR
typedef __attribute__((ext_vector_type(4))) float f32x4;

// Exact hi/lo bf16 truncation split of 8 consecutive floats.
// x = hi + lo + eps, |eps| <= 2^-15 |x|; products use hh + hl + lh (drop ll).
__device__ __forceinline__ void split8(const float4 f0, const float4 f1,
                                       bf16x8& hi, bf16x8& lo) {
  union { bf16x8 v; unsigned int u[4]; } H, L;
  const float ff[8] = {f0.x, f0.y, f0.z, f0.w, f1.x, f1.y, f1.z, f1.w};
#pragma unroll
  for (int p = 0; p < 4; ++p) {
    unsigned int b0 = __float_as_uint(ff[2 * p]);
    unsigned int b1 = __float_as_uint(ff[2 * p + 1]);
    unsigned int h0 = b0 & 0xFFFF0000u;
    unsigned int h1 = b1 & 0xFFFF0000u;
    H.u[p] = (h0 >> 16) | h1;                       // lo short = elem 2p
    float l0 = ff[2 * p]     - __uint_as_float(h0); // exact in fp32
    float l1 = ff[2 * p + 1] - __uint_as_float(h1);
    L.u[p] = (__float_as_uint(l0) >> 16) | (__float_as_uint(l1) & 0xFFFF0000u);
  }
  hi = H.v; lo = L.v;
}

// Prepass: K fp32 -> (Khi, Klo) bf16 (same element order). Also zeroes the
// per-row global candidate counters (gcnt != nullptr on the two-phase path).
__global__ __launch_bounds__(256)
void ksplit_kernel(const float* __restrict__ k,
                   unsigned short* __restrict__ khi,
                   unsigned short* __restrict__ klo,
                   int* __restrict__ gcnt) {
  const int gi = blockIdx.x * 256 + threadIdx.x;
  if (gcnt != nullptr && gi < NROWS) gcnt[gi] = 0;
  const int i = gi * 4;
  float4 x = *(const float4*)(k + i);
  ushort4 h, l;
  {
    unsigned int b;
    b = __float_as_uint(x.x); h.x = (unsigned short)(b >> 16);
    l.x = (unsigned short)(__float_as_uint(x.x - __uint_as_float(b & 0xFFFF0000u)) >> 16);
    b = __float_as_uint(x.y); h.y = (unsigned short)(b >> 16);
    l.y = (unsigned short)(__float_as_uint(x.y - __uint_as_float(b & 0xFFFF0000u)) >> 16);
    b = __float_as_uint(x.z); h.z = (unsigned short)(b >> 16);
    l.z = (unsigned short)(__float_as_uint(x.z - __uint_as_float(b & 0xFFFF0000u)) >> 16);
    b = __float_as_uint(x.w); h.w = (unsigned short)(b >> 16);
    l.w = (unsigned short)(__float_as_uint(x.w - __uint_as_float(b & 0xFFFF0000u)) >> 16);
  }
  *(ushort4*)(khi + i) = h;
  *(ushort4*)(klo + i) = l;
}

// ============ Phase A: MFMA scores + wave-local compaction ============
// Block = 16 q x 512 keys; each of 4 waves owns 128 keys. A wave solves
// Newton on ITS OWN 128-key subset (from below): tau_w <= tau* always
// (subset sum <= full sum => subset root <= tau*; Newton from below never
// overshoots). Admitting {x > tau_w} therefore keeps the full support for
// ANY data. No barriers, no LDS, 5-6 waves/SIMD (acc only 32 AGPR).
__global__ __launch_bounds__(256, 5)
void entmax_scores_kernel(const float* __restrict__ q,
                          const unsigned short* __restrict__ khi,
                          const unsigned short* __restrict__ klo,
                          int* __restrict__ gcnt,
                          int2* __restrict__ gent) {
  const int t    = threadIdx.x;
  const int wave = t >> 6;
  const int lane = t & 63;
  const int g    = lane >> 4;
  const int col  = lane & 15;

  // head-XCD affinity: bh = blk & 15 -> blk % 8 == bh % 8
  const int blk  = blockIdx.x;
  const int bh   = blk & 15;
  const int kseg = (blk >> 4) & 3;
  const int qt   = blk >> 6;                   // 0..127
  const float* qp = q + ((size_t)bh * S_ + (size_t)qt * QT_A) * D_;

  // Q fragment: A row = col, d = ks*32 + g*8 + i; fold scale/2 => *1/16.
  bf16x8 qh[2], ql[2];
#pragma unroll
  for (int ks = 0; ks < 2; ++ks) {
    const float* src = qp + col * D_ + ks * 32 + g * 8;
    float4 f0 = *(const float4*)src;
    float4 f1 = *(const float4*)(src + 4);
    f0.x *= 0.0625f; f0.y *= 0.0625f; f0.z *= 0.0625f; f0.w *= 0.0625f;
    f1.x *= 0.0625f; f1.y *= 0.0625f; f1.z *= 0.0625f; f1.w *= 0.0625f;
    split8(f0, f1, qh[ks], ql[ks]);
  }

  // QK^T over this wave's 128 keys: acc[kt][j] = x[row=g*4+j][kbase+kt*16+col]
  const int kbase = kseg * KSEG + wave * 128;
  f32x4 acc[KTW_A];
#pragma unroll
  for (int kt = 0; kt < KTW_A; ++kt) acc[kt] = (f32x4){0.f, 0.f, 0.f, 0.f};
#pragma unroll
  for (int kt = 0; kt < KTW_A; ++kt) {
    const size_t rowoff = ((size_t)bh * S_ + kbase + kt * 16 + col) * D_;
#pragma unroll
    for (int ks = 0; ks < 2; ++ks) {
      bf16x8 kh = *(const bf16x8*)(khi + rowoff + ks * 32 + g * 8);
      bf16x8 kl = *(const bf16x8*)(klo + rowoff + ks * 32 + g * 8);
      acc[kt] = __builtin_amdgcn_mfma_f32_16x16x32_bf16(qh[ks], kh, acc[kt], 0, 0, 0);
      acc[kt] = __builtin_amdgcn_mfma_f32_16x16x32_bf16(qh[ks], kl, acc[kt], 0, 0, 0);
      acc[kt] = __builtin_amdgcn_mfma_f32_16x16x32_bf16(ql[ks], kh, acc[kt], 0, 0, 0);
    }
  }

  // Wave-local row max over its 128 keys (16-lane col-group butterfly).
  float m4[4];
#pragma unroll
  for (int j = 0; j < 4; ++j) {
    float mm = acc[0][j];
#pragma unroll
    for (int kt = 1; kt < KTW_A; ++kt) mm = fmaxf(mm, acc[kt][j]);
    m4[j] = mm;
  }
#pragma unroll
  for (int off = 1; off < 16; off <<= 1)
#pragma unroll
    for (int j = 0; j < 4; ++j) m4[j] = fmaxf(m4[j], __shfl_xor(m4[j], off, 64));

  // Wave-subset Newton from tau0 = m_w - 1 (f_sub(tau0) >= 0, s1 >= 1
  // below the root -> no div-by-0; ITW_A fixed iterations).
  float tau[4];
#pragma unroll
  for (int j = 0; j < 4; ++j) tau[j] = m4[j] - 1.0f;
  for (int it = 0; it < ITW_A; ++it) {
    float s1[4] = {0, 0, 0, 0}, s2[4] = {0, 0, 0, 0};
#pragma unroll
    for (int kt = 0; kt < KTW_A; ++kt)
#pragma unroll
      for (int j = 0; j < 4; ++j) {
        float u = fmaxf(acc[kt][j] - tau[j], 0.f);
        s1[j] += u; s2[j] = fmaf(u, u, s2[j]);
      }
#pragma unroll
    for (int off = 1; off < 16; off <<= 1)
#pragma unroll
      for (int j = 0; j < 4; ++j) {
        s1[j] += __shfl_xor(s1[j], off, 64);
        s2[j] += __shfl_xor(s2[j], off, 64);
      }
#pragma unroll
    for (int j = 0; j < 4; ++j) tau[j] += (s2[j] - 1.0f) / (2.0f * s1[j]);
  }

  // Compact {x > tau_w} to the global per-row lists.
#pragma unroll
  for (int kt = 0; kt < KTW_A; ++kt)
#pragma unroll
    for (int j = 0; j < 4; ++j) {
      float x = acc[kt][j];
      if (x > tau[j]) {
        const int rowg = bh * S_ + qt * QT_A + g * 4 + j;
        int slot = atomicAdd(&gcnt[rowg], 1);
        if (slot < CAPG)
          gent[(size_t)rowg * CAPG + slot] =
              make_int2(kbase + kt * 16 + col, __float_as_int(x));
      }
    }
}

// ============ Phase B: exact per-row Newton + sparse PV ============
// One wave per row. Candidates (superset of support for any data) are in
// the global list; exact tau from Newton on <=1024 values in registers;
// support (p>0) compacted to LDS; PV over ~20-35 support keys only.
__global__ __launch_bounds__(256)
void entmax_solvepv_kernel(const float* __restrict__ v,
                           const int* __restrict__ gcnt,
                           const int2* __restrict__ gent,
                           float* __restrict__ out) {
  __shared__ int   sidx[4][SUPC];
  __shared__ float sp[4][SUPC];
  __shared__ unsigned int scnt[4];

  const int t    = threadIdx.x;
  const int wid  = t >> 6;
  const int lane = t & 63;
  const int blk  = blockIdx.x;
  const int bh   = blk & 15;                   // head-XCD affinity for V
  const int u    = blk >> 4;                   // 0..511
  const int rowg = bh * S_ + u * 4 + wid;
  const float* vp = v + (size_t)bh * S_ * D_;

  if (lane == 0) scnt[wid] = 0;
  __syncthreads();

  int n = gcnt[rowg]; if (n > CAPG) n = CAPG;
  const int2* ge = gent + (size_t)rowg * CAPG;

  float xv[16];                                // 16*64 = CAPG
#pragma unroll
  for (int r = 0; r < 16; ++r) {
    const int i = lane + (r << 6);
    xv[r] = (i < n) ? __int_as_float(ge[i].y) : -1e30f;
  }

  // tau0 = (row max) - 1: the global max is always admitted (x_max > tau*).
  float mx = xv[0];
#pragma unroll
  for (int r = 1; r < 16; ++r) mx = fmaxf(mx, xv[r]);
#pragma unroll
  for (int off = 1; off < 64; off <<= 1) mx = fmaxf(mx, __shfl_xor(mx, off, 64));
  float tau = mx - 1.0f;

  for (int it = 0; it < BMAXIT; ++it) {
    float s1 = 0.f, s2 = 0.f;
#pragma unroll
    for (int r = 0; r < 16; ++r) {
      float uu = fmaxf(xv[r] - tau, 0.f);
      s1 += uu; s2 = fmaf(uu, uu, s2);
    }
#pragma unroll
    for (int off = 1; off < 64; off <<= 1) {
      s1 += __shfl_xor(s1, off, 64);
      s2 += __shfl_xor(s2, off, 64);
    }
    float step = (s2 - 1.0f) / (2.0f * s1);    // s1 >= 1 below the root
    tau += step;
    if (step < 1e-7f) break;                   // lane-uniform
  }

  // Support -> LDS (same-wave LDS ops are in-order; no barrier needed).
#pragma unroll
  for (int r = 0; r < 16; ++r) {
    const int i = lane + (r << 6);
    if (i < n) {
      float uu = xv[r] - tau;
      if (uu > 0.f) {
        unsigned int slot = atomicAdd(&scnt[wid], 1u);
        if (slot < SUPC) { sidx[wid][slot] = ge[i].x; sp[wid][slot] = uu * uu; }
      }
    }
  }
  int sn = (int)scnt[wid]; if (sn > SUPC) sn = SUPC;

  float s = 0.f;
#pragma unroll 4
  for (int i = 0; i < sn; ++i)
    s = fmaf(sp[wid][i], vp[(size_t)sidx[wid][i] * D_ + lane], s);
  out[(size_t)rowg * D_ + lane] = s;
}

// ============ Fallback: R5 single-kernel path (verbatim) ============
template <bool PRE>
__global__ __launch_bounds__(BLOCK_F, 4)
void entmax_attn_kernel(const float* __restrict__ q,
                        const float* __restrict__ k,
                        const unsigned short* __restrict__ khi,
                        const unsigned short* __restrict__ klo,
                        const float* __restrict__ v,
                        float* __restrict__ out) {
  __shared__ float redM[NW_F][QT_F];
  __shared__ float redS1[2][NW_F][QT_F];
  __shared__ float redS2[2][NW_F][QT_F];
  __shared__ unsigned int cnt[QT_F];
  __shared__ int   lidx[QT_F][CAP_F];
  __shared__ float lval[QT_F][CAP_F];

  const int t    = threadIdx.x;
  const int wid  = t >> 6;
  const int lane = t & 63;
  const int g    = lane >> 4;
  const int col  = lane & 15;
  const int rowL = lane & 31;

  const int blk = blockIdx.x;
  const int bh  = blk & 15;
  const int qt  = blk >> 4;
  const float* qp = q + ((size_t)bh * S_ + (size_t)qt * QT_F) * D_;
  const float* kp = k + (size_t)bh * S_ * D_;
  const float* vp = v + (size_t)bh * S_ * D_;
  float* op = out + ((size_t)bh * S_ + (size_t)qt * QT_F) * D_;

  if (t < QT_F) cnt[t] = 0;

  bf16x8 qh[2][2], ql[2][2];
#pragma unroll
  for (int f = 0; f < 2; ++f)
#pragma unroll
    for (int ks = 0; ks < 2; ++ks) {
      const float* src = qp + (f * 16 + col) * D_ + ks * 32 + g * 8;
      float4 f0 = *(const float4*)src;
      float4 f1 = *(const float4*)(src + 4);
      f0.x *= 0.0625f; f0.y *= 0.0625f; f0.z *= 0.0625f; f0.w *= 0.0625f;
      f1.x *= 0.0625f; f1.y *= 0.0625f; f1.z *= 0.0625f; f1.w *= 0.0625f;
      split8(f0, f1, qh[f][ks], ql[f][ks]);
    }

  f32x4 acc[2][KTW_F];
#pragma unroll
  for (int f = 0; f < 2; ++f)
#pragma unroll
    for (int kt = 0; kt < KTW_F; ++kt) acc[f][kt] = (f32x4){0.f, 0.f, 0.f, 0.f};
#pragma unroll
  for (int kt = 0; kt < KTW_F; ++kt) {
    const size_t rowoff = (size_t)(wid * 128 + kt * 16 + col) * D_;
#pragma unroll
    for (int ks = 0; ks < 2; ++ks) {
      bf16x8 kh, kl;
      if (PRE) {
        const size_t eoff = (size_t)bh * S_ * D_ + rowoff + ks * 32 + g * 8;
        kh = *(const bf16x8*)(khi + eoff);
        kl = *(const bf16x8*)(klo + eoff);
      } else {
        const float* src = kp + rowoff + ks * 32 + g * 8;
        split8(*(const float4*)src, *(const float4*)(src + 4), kh, kl);
      }
#pragma unroll
      for (int f = 0; f < 2; ++f) {
        acc[f][kt] = __builtin_amdgcn_mfma_f32_16x16x32_bf16(qh[f][ks], kh, acc[f][kt], 0, 0, 0);
        acc[f][kt] = __builtin_amdgcn_mfma_f32_16x16x32_bf16(qh[f][ks], kl, acc[f][kt], 0, 0, 0);
        acc[f][kt] = __builtin_amdgcn_mfma_f32_16x16x32_bf16(ql[f][ks], kh, acc[f][kt], 0, 0, 0);
      }
    }
  }

  {
    float m4[2][4];
#pragma unroll
    for (int f = 0; f < 2; ++f)
#pragma unroll
      for (int j = 0; j < 4; ++j) {
        float mm = acc[f][0][j];
#pragma unroll
        for (int kt = 1; kt < KTW_F; ++kt) mm = fmaxf(mm, acc[f][kt][j]);
        m4[f][j] = mm;
      }
#pragma unroll
    for (int off = 1; off < 16; off <<= 1)
#pragma unroll
      for (int f = 0; f < 2; ++f)
#pragma unroll
        for (int j = 0; j < 4; ++j)
          m4[f][j] = fmaxf(m4[f][j], __shfl_xor(m4[f][j], off, 64));
    if (col == 0) {
#pragma unroll
      for (int f = 0; f < 2; ++f)
#pragma unroll
        for (int j = 0; j < 4; ++j) redM[wid][f * 16 + g * 4 + j] = m4[f][j];
    }
  }
  __syncthreads();

  float tauRow;
  {
    float mm = redM[0][rowL];
#pragma unroll
    for (int w = 1; w < NW_F; ++w) mm = fmaxf(mm, redM[w][rowL]);
    tauRow = mm - 1.0f;
  }
  float tau[2][4];
#pragma unroll
  for (int f = 0; f < 2; ++f)
#pragma unroll
    for (int j = 0; j < 4; ++j) tau[f][j] = __shfl(tauRow, f * 16 + g * 4 + j);

  for (int it = 0; it < ITPRE_F; ++it) {
    const int b = it & 1;
    float s1[2][4] = {{0,0,0,0},{0,0,0,0}}, s2[2][4] = {{0,0,0,0},{0,0,0,0}};
#pragma unroll
    for (int kt = 0; kt < KTW_F; ++kt)
#pragma unroll
      for (int f = 0; f < 2; ++f)
#pragma unroll
        for (int j = 0; j < 4; ++j) {
          float u = fmaxf(acc[f][kt][j] - tau[f][j], 0.f);
          s1[f][j] += u; s2[f][j] = fmaf(u, u, s2[f][j]);
        }
#pragma unroll
    for (int off = 1; off < 16; off <<= 1)
#pragma unroll
      for (int f = 0; f < 2; ++f)
#pragma unroll
        for (int j = 0; j < 4; ++j) {
          s1[f][j] += __shfl_xor(s1[f][j], off, 64);
          s2[f][j] += __shfl_xor(s2[f][j], off, 64);
        }
    if (col == 0) {
#pragma unroll
      for (int f = 0; f < 2; ++f)
#pragma unroll
        for (int j = 0; j < 4; ++j) {
          redS1[b][wid][f * 16 + g * 4 + j] = s1[f][j];
          redS2[b][wid][f * 16 + g * 4 + j] = s2[f][j];
        }
    }
    __syncthreads();
    const float* pS = (lane < 32) ? &redS1[b][0][rowL] : &redS2[b][0][rowL];
    float T = 0.f;
#pragma unroll
    for (int w = 0; w < NW_F; ++w) T += pS[w * QT_F];
    float other = __shfl_xor(T, 32, 64);
    float step_r = (other - 1.0f) / (2.0f * T);
    if (lane < 32) tauRow += step_r;
#pragma unroll
    for (int f = 0; f < 2; ++f)
#pragma unroll
      for (int j = 0; j < 4; ++j)
        tau[f][j] += __shfl(step_r, f * 16 + g * 4 + j);
  }

#pragma unroll
  for (int kt = 0; kt < KTW_F; ++kt)
#pragma unroll
    for (int f = 0; f < 2; ++f)
#pragma unroll
      for (int j = 0; j < 4; ++j) {
        float x = acc[f][kt][j];
        if (x > tau[f][j]) {
          const int row = f * 16 + g * 4 + j;
          unsigned int s = atomicAdd(&cnt[row], 1u);
          if (s < CAP_F) {
            lidx[row][s] = wid * 128 + kt * 16 + col;
            lval[row][s] = x;
          }
        }
      }
  __syncthreads();

  for (int rr = 0; rr < 2; ++rr) {
    const int row = wid * 2 + rr;
    int n = (int)cnt[row]; if (n > CAP_F) n = CAP_F;
    float xv[4];
#pragma unroll
    for (int r = 0; r < 4; ++r) {
      const int i = lane + 64 * r;
      xv[r] = (i < n) ? lval[row][i] : -1e30f;
    }
    float tw = __shfl(tauRow, row);
    for (int it = 0; it < WMAXIT_F; ++it) {
      float s1 = 0.f, s2 = 0.f;
#pragma unroll
      for (int r = 0; r < 4; ++r) {
        float u = fmaxf(xv[r] - tw, 0.f);
        s1 += u; s2 = fmaf(u, u, s2);
      }
#pragma unroll
      for (int off = 1; off < 64; off <<= 1) {
        s1 += __shfl_xor(s1, off, 64);
        s2 += __shfl_xor(s2, off, 64);
      }
      float step = (s2 - 1.0f) / (2.0f * s1);
      tw += step;
      if (step < 1e-7f) break;
    }
#pragma unroll
    for (int r = 0; r < 4; ++r) {
      const int i = lane + 64 * r;
      if (i < n) {
        float u = fmaxf(xv[r] - tw, 0.f);
        lval[row][i] = u * u;
      }
    }
    float s = 0.f;
#pragma unroll 4
    for (int i = 0; i < n; ++i) {
      s = fmaf(lval[row][i], vp[(size_t)lidx[row][i] * D_ + lane], s);
    }
    op[row * D_ + lane] = s;
  }
}

extern "C" void kernel_launch(void* const* d_in, const int* in_sizes, int n_in,
                              void* d_out, int out_size, void* d_ws, size_t ws_size,
                              hipStream_t stream) {
  const float* q = (const float*)d_in[0];
  const float* k = (const float*)d_in[1];
  const float* v = (const float*)d_in[2];
  float* out = (float*)d_out;

  const size_t khi_b  = (size_t)KELEMS * 2;                 // 4 MB
  const size_t cnt_b  = (size_t)NROWS * 4;                  // 128 KB
  const size_t ent_b  = (size_t)NROWS * CAPG * 8;           // 256 MB
  const size_t need_pre  = 2 * khi_b;                       // 8.4 MB
  const size_t need_full = 2 * khi_b + cnt_b + ent_b;       // ~264 MB

  if (d_ws != nullptr && ws_size >= need_full) {
    unsigned short* khi = (unsigned short*)d_ws;
    unsigned short* klo = khi + KELEMS;
    int*  gcnt = (int*)((char*)d_ws + 2 * khi_b);
    int2* gent = (int2*)((char*)d_ws + 2 * khi_b + cnt_b);
    ksplit_kernel<<<dim3(KELEMS / (256 * 4)), dim3(256), 0, stream>>>(k, khi, klo, gcnt);
    entmax_scores_kernel<<<dim3(BH_ * 4 * (S_ / QT_A)), dim3(256), 0, stream>>>(
        q, khi, klo, gcnt, gent);
    entmax_solvepv_kernel<<<dim3(BH_ * (S_ / 4)), dim3(256), 0, stream>>>(
        v, gcnt, gent, out);
  } else if (d_ws != nullptr && ws_size >= need_pre) {
    unsigned short* khi = (unsigned short*)d_ws;
    unsigned short* klo = khi + KELEMS;
    ksplit_kernel<<<dim3(KELEMS / (256 * 4)), dim3(256), 0, stream>>>(k, khi, klo, nullptr);
    entmax_attn_kernel<true><<<dim3(BH_ * (S_ / QT_F)), dim3(BLOCK_F), 0, stream>>>(
        q, k, khi, klo, v, out);
  } else {
    entmax_attn_kernel<false><<<dim3(BH_ * (S_ / QT_F)), dim3(BLOCK_F), 0, stream>>>(
        q, k, nullptr, nullptr, v, out);
  }
}